// Round 1
// baseline (58.228 us; speedup 1.0000x reference)
//
#include <hip/hip_runtime.h>
#include <math.h>

#define H_DIM 128
#define W_DIM 128
#define BATCH 8
#define NPIX (H_DIM * W_DIM)
#define INF_I (1 << 28)
#define NT 1024

// Fully fused distance transform. One block per output row i, 1024 threads.
// No workspace, no intermediate global buffer: each block builds the
// batch-union boundary mask in LDS itself (input is L2-resident: 512 KB
// shared by all 16 blocks on an XCD), then runs the separable DT with the
// 128-iteration passes split 8 ways across the 8 thread segments.
__global__ __launch_bounds__(NT) void fused_dt_kernel(const float* __restrict__ fm,
                                                      float* __restrict__ out) {
    const int i = blockIdx.x;      // output row
    const int tid = threadIdx.x;   // 0..1023

    __shared__ unsigned char maskS[NPIX];   // 16 KB
    __shared__ int part[8][W_DIM];          // 4 KB, reused for both passes' partials
    __shared__ int gS[W_DIM];
    __shared__ float distS[W_DIM];

    // Phase 1: boundary mask, unioned over 8 batches, straight into LDS.
    // 4096 float4 per image; thread handles 4 float4 positions x 8 batches.
    // Loads are fully coalesced (consecutive threads -> consecutive float4).
    const float4* fm4 = (const float4*)fm;
    #pragma unroll
    for (int q = 0; q < 4; ++q) {
        const int f = q * NT + tid;         // float4 index within an image, 0..4095
        bool m0 = false, m1 = false, m2 = false, m3 = false;
        #pragma unroll
        for (int b = 0; b < BATCH; ++b) {
            float4 v = fm4[b * 4096 + f];
            m0 |= v.x > 0.5f;
            m1 |= v.y > 0.5f;
            m2 |= v.z > 0.5f;
            m3 |= v.w > 0.5f;
        }
        uchar4 mm;
        mm.x = (unsigned char)m0;
        mm.y = (unsigned char)m1;
        mm.z = (unsigned char)m2;
        mm.w = (unsigned char)m3;
        ((uchar4*)maskS)[f] = mm;
    }
    __syncthreads();

    const int w   = tid & 127;   // column (pass B) / output col j (pass C)
    const int seg = tid >> 7;    // 0..7: h-slice, w-slice, and batch index

    // Pass B: column DT. g[w] = min_h (mask[h][w] ? (i-h)^2 : INF), h split 8 ways.
    {
        int g = INF_I;
        const int h0 = seg * 16;
        #pragma unroll
        for (int k = 0; k < 16; ++k) {
            const int h = h0 + k;
            const int d = i - h;
            if (maskS[h * W_DIM + w]) g = min(g, d * d);
        }
        part[seg][w] = g;
    }
    __syncthreads();
    if (tid < W_DIM) {
        int g = part[0][tid];
        #pragma unroll
        for (int s = 1; s < 8; ++s) g = min(g, part[s][tid]);
        gS[tid] = g;
    }
    __syncthreads();

    // Pass C: row DT. best[j] = min_w (g[w] + (j-w)^2), w split 8 ways.
    // gS[wc] is wave-uniform per iteration -> LDS broadcast, conflict-free.
    {
        int best = INF_I;
        const int w0 = seg * 16;
        #pragma unroll
        for (int k = 0; k < 16; ++k) {
            const int wc = w0 + k;
            const int d = w - wc;                    // j = w
            best = min(best, gS[wc] + d * d);        // max 2^28 + 16129, no overflow
        }
        part[seg][w] = best;    // safe reuse: all pass-B readers passed the barrier
    }
    __syncthreads();
    if (tid < W_DIM) {
        int best = part[0][tid];
        #pragma unroll
        for (int s = 1; s < 8; ++s) best = min(best, part[s][tid]);
        distS[tid] = (best >= INF_I) ? INFINITY : sqrtf((float)best);
    }
    __syncthreads();

    // Write row i broadcast across the 8 batch images: exactly one element
    // per thread, coalesced 256 B per wave.
    out[seg * NPIX + i * W_DIM + w] = distS[w];
}

extern "C" void kernel_launch(void* const* d_in, const int* in_sizes, int n_in,
                              void* d_out, int out_size, void* d_ws, size_t ws_size,
                              hipStream_t stream) {
    const float* fm = (const float*)d_in[0];
    float* out = (float*)d_out;
    (void)d_ws; (void)ws_size;   // workspace deliberately untouched

    fused_dt_kernel<<<H_DIM, NT, 0, stream>>>(fm, out);
}